// Round 1
// baseline (227.302 us; speedup 1.0000x reference)
//
#include <hip/hip_runtime.h>

#define EPS 1e-7f
#define NCH 29

// MLP sizes: 7 -> 5 -> 4 -> 4 -> 3, per-channel weights.
// W0: [c][7][5] (35/ch)  b0: [c][5]
// W1: [c][5][4] (20/ch)  b1: [c][4]
// W2: [c][4][4] (16/ch)  b2: [c][4]
// W3: [c][4][3] (12/ch)  b3: [c][3]

__device__ __forceinline__ void mlp7(const float x[7],
    const float* __restrict__ W0, const float* __restrict__ b0,
    const float* __restrict__ W1, const float* __restrict__ b1,
    const float* __restrict__ W2, const float* __restrict__ b2,
    const float* __restrict__ W3, const float* __restrict__ b3,
    float e[3])
{
    float h0[5];
#pragma unroll
    for (int h = 0; h < 5; ++h) {
        float a = b0[h];
#pragma unroll
        for (int f = 0; f < 7; ++f) a = fmaf(x[f], W0[f * 5 + h], a);
        h0[h] = fmaxf(a, 0.0f);
    }
    float h1[4];
#pragma unroll
    for (int k = 0; k < 4; ++k) {
        float a = b1[k];
#pragma unroll
        for (int h = 0; h < 5; ++h) a = fmaf(h0[h], W1[h * 4 + k], a);
        h1[k] = fmaxf(a, 0.0f);
    }
    float h2[4];
#pragma unroll
    for (int k = 0; k < 4; ++k) {
        float a = b2[k];
#pragma unroll
        for (int h = 0; h < 4; ++h) a = fmaf(h1[h], W2[h * 4 + k], a);
        h2[k] = fmaxf(a, 0.0f);
    }
    float l[3];
#pragma unroll
    for (int k = 0; k < 3; ++k) {
        float a = b3[k];
#pragma unroll
        for (int h = 0; h < 4; ++h) a = fmaf(h2[h], W3[h * 3 + k], a);
        l[k] = a;
    }
    float m = fmaxf(l[0], fmaxf(l[1], l[2]));
    float e0 = __expf(l[0] - m);
    float e1 = __expf(l[1] - m);
    float e2 = __expf(l[2] - m);
    float rs = 1.0f / (e0 + e1 + e2);
    e[0] = e0 * rs; e[1] = e1 * rs; e[2] = e2 * rs;
}

__global__ __launch_bounds__(256) void lps_kernel(
    const float* __restrict__ tau, const float* __restrict__ mu, const float* __restrict__ mu_bar,
    const float* __restrict__ lw, const float* __restrict__ h2o, const float* __restrict__ o3,
    const float* __restrict__ co2, const float* __restrict__ uu, const float* __restrict__ n2o,
    const float* __restrict__ ch4,
    const float* __restrict__ Wd0, const float* __restrict__ bd0,
    const float* __restrict__ Wf0, const float* __restrict__ bf0,
    const float* __restrict__ Wd1, const float* __restrict__ bd1,
    const float* __restrict__ Wf1, const float* __restrict__ bf1,
    const float* __restrict__ Wd2, const float* __restrict__ bd2,
    const float* __restrict__ Wf2, const float* __restrict__ bf2,
    const float* __restrict__ Wd3, const float* __restrict__ bd3,
    const float* __restrict__ Wf3, const float* __restrict__ bf3,
    float* __restrict__ out, int N)
{
    int n = blockIdx.x * blockDim.x + threadIdx.x;
    if (n >= N) return;

    const float rmu  = 1.0f / (mu[n] + EPS);
    const float rmub = 1.0f / (mu_bar[n] + EPS);

    float cons[7];
    cons[0] = lw[n]; cons[1] = h2o[n]; cons[2] = o3[n]; cons[3] = co2[n];
    cons[4] = uu[n]; cons[5] = n2o[n]; cons[6] = ch4[n];

    float xd[7], xf[7];
#pragma unroll
    for (int f = 0; f < 7; ++f) { xd[f] = cons[f] * rmu; xf[f] = cons[f] * rmub; }

    const float* __restrict__ taun = tau + (size_t)n * NCH;
    float* __restrict__ outn = out + (size_t)n * NCH * 8;

    for (int c = 0; c < NCH; ++c) {
        float tv = taun[c];
        float t_dir = __expf(-tv * rmu);
        float t_dif = __expf(-tv * rmub);

        float ed[3], ef[3];
        mlp7(xd, Wd0 + c * 35, bd0 + c * 5, Wd1 + c * 20, bd1 + c * 4,
                 Wd2 + c * 16, bd2 + c * 4, Wd3 + c * 12, bd3 + c * 3, ed);
        mlp7(xf, Wf0 + c * 35, bf0 + c * 5, Wf1 + c * 20, bf1 + c * 4,
                 Wf2 + c * 16, bf2 + c * 4, Wf3 + c * 12, bf3 + c * 3, ef);

        float4 o0 = make_float4(t_dir, t_dif, ed[0], ed[1]);
        float4 o1 = make_float4(ed[2], ef[0], ef[1], ef[2]);
        float4* op = (float4*)(outn + c * 8);
        op[0] = o0;
        op[1] = o1;
    }
}

extern "C" void kernel_launch(void* const* d_in, const int* in_sizes, int n_in,
                              void* d_out, int out_size, void* d_ws, size_t ws_size,
                              hipStream_t stream) {
    const float* tau    = (const float*)d_in[0];
    const float* mu     = (const float*)d_in[1];
    const float* mu_bar = (const float*)d_in[2];
    const float* lw     = (const float*)d_in[3];
    const float* h2o    = (const float*)d_in[4];
    const float* o3     = (const float*)d_in[5];
    const float* co2    = (const float*)d_in[6];
    const float* uu     = (const float*)d_in[7];
    const float* n2o    = (const float*)d_in[8];
    const float* ch4    = (const float*)d_in[9];

    const float* Wd0 = (const float*)d_in[10];
    const float* bd0 = (const float*)d_in[11];
    const float* Wf0 = (const float*)d_in[12];
    const float* bf0 = (const float*)d_in[13];
    const float* Wd1 = (const float*)d_in[14];
    const float* bd1 = (const float*)d_in[15];
    const float* Wf1 = (const float*)d_in[16];
    const float* bf1 = (const float*)d_in[17];
    const float* Wd2 = (const float*)d_in[18];
    const float* bd2 = (const float*)d_in[19];
    const float* Wf2 = (const float*)d_in[20];
    const float* bf2 = (const float*)d_in[21];
    const float* Wd3 = (const float*)d_in[22];
    const float* bd3 = (const float*)d_in[23];
    const float* Wf3 = (const float*)d_in[24];
    const float* bf3 = (const float*)d_in[25];

    float* out = (float*)d_out;
    int N = in_sizes[1];  // mu has N elements

    int threads = 256;
    int blocks = (N + threads - 1) / threads;
    lps_kernel<<<blocks, threads, 0, stream>>>(
        tau, mu, mu_bar, lw, h2o, o3, co2, uu, n2o, ch4,
        Wd0, bd0, Wf0, bf0, Wd1, bd1, Wf1, bf1,
        Wd2, bd2, Wf2, bf2, Wd3, bd3, Wf3, bf3,
        out, N);
}

// Round 2
// 139.232 us; speedup vs baseline: 1.6325x; 1.6325x over previous
//
#include <hip/hip_runtime.h>

#define EPS 1e-7f
#define NCH 29
#define SAMP_PER_BLK 64
#define OUT_PER_SAMP 232   // 29 channels * 8 floats

// MLP sizes: 7 -> 5 -> 4 -> 4 -> 3, per-channel weights.
// W0: [c][7][5] (35/ch)  b0: [c][5]
// W1: [c][5][4] (20/ch)  b1: [c][4]
// W2: [c][4][4] (16/ch)  b2: [c][4]
// W3: [c][4][3] (12/ch)  b3: [c][3]

__device__ __forceinline__ void mlp7(const float x[7],
    const float* __restrict__ W0, const float* __restrict__ b0,
    const float* __restrict__ W1, const float* __restrict__ b1,
    const float* __restrict__ W2, const float* __restrict__ b2,
    const float* __restrict__ W3, const float* __restrict__ b3,
    float e[3])
{
    float h0[5];
#pragma unroll
    for (int h = 0; h < 5; ++h) {
        float a = b0[h];
#pragma unroll
        for (int f = 0; f < 7; ++f) a = fmaf(x[f], W0[f * 5 + h], a);
        h0[h] = fmaxf(a, 0.0f);
    }
    float h1[4];
#pragma unroll
    for (int k = 0; k < 4; ++k) {
        float a = b1[k];
#pragma unroll
        for (int h = 0; h < 5; ++h) a = fmaf(h0[h], W1[h * 4 + k], a);
        h1[k] = fmaxf(a, 0.0f);
    }
    float h2[4];
#pragma unroll
    for (int k = 0; k < 4; ++k) {
        float a = b2[k];
#pragma unroll
        for (int h = 0; h < 4; ++h) a = fmaf(h1[h], W2[h * 4 + k], a);
        h2[k] = fmaxf(a, 0.0f);
    }
    float l[3];
#pragma unroll
    for (int k = 0; k < 3; ++k) {
        float a = b3[k];
#pragma unroll
        for (int h = 0; h < 4; ++h) a = fmaf(h2[h], W3[h * 3 + k], a);
        l[k] = a;
    }
    float m = fmaxf(l[0], fmaxf(l[1], l[2]));
    float e0 = __expf(l[0] - m);
    float e1 = __expf(l[1] - m);
    float e2 = __expf(l[2] - m);
    float rs = 1.0f / (e0 + e1 + e2);
    e[0] = e0 * rs; e[1] = e1 * rs; e[2] = e2 * rs;
}

__global__ __launch_bounds__(256) void lps_kernel(
    const float* __restrict__ tau, const float* __restrict__ mu, const float* __restrict__ mu_bar,
    const float* __restrict__ lw, const float* __restrict__ h2o, const float* __restrict__ o3,
    const float* __restrict__ co2, const float* __restrict__ uu, const float* __restrict__ n2o,
    const float* __restrict__ ch4,
    const float* __restrict__ Wd0, const float* __restrict__ bd0,
    const float* __restrict__ Wf0, const float* __restrict__ bf0,
    const float* __restrict__ Wd1, const float* __restrict__ bd1,
    const float* __restrict__ Wf1, const float* __restrict__ bf1,
    const float* __restrict__ Wd2, const float* __restrict__ bd2,
    const float* __restrict__ Wf2, const float* __restrict__ bf2,
    const float* __restrict__ Wd3, const float* __restrict__ bd3,
    const float* __restrict__ Wf3, const float* __restrict__ bf3,
    float* __restrict__ out, int N)
{
    __shared__ __align__(16) float obuf[SAMP_PER_BLK * OUT_PER_SAMP]; // 59392 B

    const int tid  = threadIdx.x;
    const int lane = tid & 63;
    // wave id, forced wave-uniform so channel index (and thus all weight
    // addresses) are scalar -> s_load into SGPRs, zero per-lane weight traffic.
    const int wid  = __builtin_amdgcn_readfirstlane(tid >> 6);

    const long long blk_base = (long long)blockIdx.x * SAMP_PER_BLK;
    const int sg = (int)blk_base + lane;   // this lane's sample

    if (sg < N) {
        const float rmu  = 1.0f / (mu[sg] + EPS);
        const float rmub = 1.0f / (mu_bar[sg] + EPS);
        const float nrmu  = -rmu;
        const float nrmub = -rmub;

        float cons[7];
        cons[0] = lw[sg]; cons[1] = h2o[sg]; cons[2] = o3[sg]; cons[3] = co2[sg];
        cons[4] = uu[sg]; cons[5] = n2o[sg]; cons[6] = ch4[sg];

        float xd[7], xf[7];
#pragma unroll
        for (int f = 0; f < 7; ++f) { xd[f] = cons[f] * rmu; xf[f] = cons[f] * rmub; }

        const float* taun = tau + (size_t)sg * NCH;
        float4* ob4 = (float4*)obuf;

        for (int c = wid; c < NCH; c += 4) {
            float tv = taun[c];
            float t_dir = __expf(tv * nrmu);
            float t_dif = __expf(tv * nrmub);

            float ed[3], ef[3];
            mlp7(xd, Wd0 + c * 35, bd0 + c * 5, Wd1 + c * 20, bd1 + c * 4,
                     Wd2 + c * 16, bd2 + c * 4, Wd3 + c * 12, bd3 + c * 3, ed);
            mlp7(xf, Wf0 + c * 35, bf0 + c * 5, Wf1 + c * 20, bf1 + c * 4,
                     Wf2 + c * 16, bf2 + c * 4, Wf3 + c * 12, bf3 + c * 3, ef);

            int base4 = lane * (OUT_PER_SAMP / 4) + c * 2;
            ob4[base4]     = make_float4(t_dir, t_dif, ed[0], ed[1]);
            ob4[base4 + 1] = make_float4(ed[2], ef[0], ef[1], ef[2]);
        }
    }

    __syncthreads();

    // Stream LDS -> global, fully coalesced full-line writes.
    int nsamp = N - (int)blk_base;
    if (nsamp > SAMP_PER_BLK) nsamp = SAMP_PER_BLK;
    const int tot4 = nsamp * (OUT_PER_SAMP / 4);      // float4 count
    float4* out4 = (float4*)(out + blk_base * OUT_PER_SAMP);
    const float4* ob4 = (const float4*)obuf;
    for (int i = tid; i < tot4; i += 256) {
        out4[i] = ob4[i];
    }
}

extern "C" void kernel_launch(void* const* d_in, const int* in_sizes, int n_in,
                              void* d_out, int out_size, void* d_ws, size_t ws_size,
                              hipStream_t stream) {
    const float* tau    = (const float*)d_in[0];
    const float* mu     = (const float*)d_in[1];
    const float* mu_bar = (const float*)d_in[2];
    const float* lw     = (const float*)d_in[3];
    const float* h2o    = (const float*)d_in[4];
    const float* o3     = (const float*)d_in[5];
    const float* co2    = (const float*)d_in[6];
    const float* uu     = (const float*)d_in[7];
    const float* n2o    = (const float*)d_in[8];
    const float* ch4    = (const float*)d_in[9];

    const float* Wd0 = (const float*)d_in[10];
    const float* bd0 = (const float*)d_in[11];
    const float* Wf0 = (const float*)d_in[12];
    const float* bf0 = (const float*)d_in[13];
    const float* Wd1 = (const float*)d_in[14];
    const float* bd1 = (const float*)d_in[15];
    const float* Wf1 = (const float*)d_in[16];
    const float* bf1 = (const float*)d_in[17];
    const float* Wd2 = (const float*)d_in[18];
    const float* bd2 = (const float*)d_in[19];
    const float* Wf2 = (const float*)d_in[20];
    const float* bf2 = (const float*)d_in[21];
    const float* Wd3 = (const float*)d_in[22];
    const float* bd3 = (const float*)d_in[23];
    const float* Wf3 = (const float*)d_in[24];
    const float* bf3 = (const float*)d_in[25];

    float* out = (float*)d_out;
    int N = in_sizes[1];  // mu has N elements

    int blocks = (N + SAMP_PER_BLK - 1) / SAMP_PER_BLK;
    lps_kernel<<<blocks, 256, 0, stream>>>(
        tau, mu, mu_bar, lw, h2o, o3, co2, uu, n2o, ch4,
        Wd0, bd0, Wf0, bf0, Wd1, bd1, Wf1, bf1,
        Wd2, bd2, Wf2, bf2, Wd3, bd3, Wf3, bf3,
        out, N);
}

// Round 3
// 83.911 us; speedup vs baseline: 2.7088x; 1.6593x over previous
//
#include <hip/hip_runtime.h>

#define EPS 1e-7f
#define NCH 29
#define SPB 128          // samples per block: 64 lanes x 2 packed samples
#define ROWF4 17         // padded float4 stride per sample in obuf (16 + 1)

// MLP sizes: 7 -> 5 -> 4 -> 4 -> 3, per-channel weights.
// W0: [c][7][5]  b0: [c][5]
// W1: [c][5][4]  b1: [c][4]
// W2: [c][4][4]  b2: [c][4]
// W3: [c][4][3]  b3: [c][3]

typedef float f32x2 __attribute__((ext_vector_type(2)));

__device__ __forceinline__ f32x2 splat2(float v) { f32x2 r; r.x = v; r.y = v; return r; }
__device__ __forceinline__ f32x2 fma2(f32x2 a, f32x2 b, f32x2 c) {
    return __builtin_elementwise_fma(a, b, c);
}
__device__ __forceinline__ f32x2 max2(f32x2 a, f32x2 b) {
    return __builtin_elementwise_max(a, b);
}
__device__ __forceinline__ f32x2 expc2(f32x2 a) {
    f32x2 r; r.x = __expf(a.x); r.y = __expf(a.y); return r;
}
__device__ __forceinline__ f32x2 rcp2(f32x2 a) {
    f32x2 r; r.x = __builtin_amdgcn_rcpf(a.x); r.y = __builtin_amdgcn_rcpf(a.y); return r;
}

// Packed 2-sample MLP: weights are wave-uniform scalars (SGPR), data is f32x2
// (two samples per lane) -> v_pk_fma_f32.
__device__ __forceinline__ void mlp7p(const f32x2 x[7],
    const float* __restrict__ W0, const float* __restrict__ b0,
    const float* __restrict__ W1, const float* __restrict__ b1,
    const float* __restrict__ W2, const float* __restrict__ b2,
    const float* __restrict__ W3, const float* __restrict__ b3,
    f32x2 e[3])
{
    const f32x2 zero = splat2(0.0f);
    f32x2 h0[5];
#pragma unroll
    for (int h = 0; h < 5; ++h) {
        f32x2 a = splat2(b0[h]);
#pragma unroll
        for (int f = 0; f < 7; ++f) a = fma2(x[f], splat2(W0[f * 5 + h]), a);
        h0[h] = max2(a, zero);
    }
    f32x2 h1[4];
#pragma unroll
    for (int k = 0; k < 4; ++k) {
        f32x2 a = splat2(b1[k]);
#pragma unroll
        for (int h = 0; h < 5; ++h) a = fma2(h0[h], splat2(W1[h * 4 + k]), a);
        h1[k] = max2(a, zero);
    }
    f32x2 h2[4];
#pragma unroll
    for (int k = 0; k < 4; ++k) {
        f32x2 a = splat2(b2[k]);
#pragma unroll
        for (int h = 0; h < 4; ++h) a = fma2(h1[h], splat2(W2[h * 4 + k]), a);
        h2[k] = max2(a, zero);
    }
    f32x2 l[3];
#pragma unroll
    for (int k = 0; k < 3; ++k) {
        f32x2 a = splat2(b3[k]);
#pragma unroll
        for (int h = 0; h < 4; ++h) a = fma2(h2[h], splat2(W3[h * 3 + k]), a);
        l[k] = a;
    }
    f32x2 m = max2(l[0], max2(l[1], l[2]));
    f32x2 e0 = expc2(l[0] - m);
    f32x2 e1 = expc2(l[1] - m);
    f32x2 e2 = expc2(l[2] - m);
    f32x2 rs = rcp2(e0 + e1 + e2);
    e[0] = e0 * rs; e[1] = e1 * rs; e[2] = e2 * rs;
}

__global__ __launch_bounds__(256, 4) void lps_kernel(
    const float* __restrict__ tau, const float* __restrict__ mu, const float* __restrict__ mu_bar,
    const float* __restrict__ lw, const float* __restrict__ h2o, const float* __restrict__ o3,
    const float* __restrict__ co2, const float* __restrict__ uu, const float* __restrict__ n2o,
    const float* __restrict__ ch4,
    const float* __restrict__ Wd0, const float* __restrict__ bd0,
    const float* __restrict__ Wf0, const float* __restrict__ bf0,
    const float* __restrict__ Wd1, const float* __restrict__ bd1,
    const float* __restrict__ Wf1, const float* __restrict__ bf1,
    const float* __restrict__ Wd2, const float* __restrict__ bd2,
    const float* __restrict__ Wf2, const float* __restrict__ bf2,
    const float* __restrict__ Wd3, const float* __restrict__ bd3,
    const float* __restrict__ Wf3, const float* __restrict__ bf3,
    float* __restrict__ out, int N)
{
    __shared__ __align__(16) float4 obuf[SPB * ROWF4];  // 34816 B

    const int tid  = threadIdx.x;
    const int lane = tid & 63;
    const int wid  = __builtin_amdgcn_readfirstlane(tid >> 6);

    const int base = blockIdx.x * SPB;
    const int s0 = base + lane;
    const int s1 = s0 + 64;
    const int i0 = (s0 < N) ? s0 : (N - 1);
    const int i1 = (s1 < N) ? s1 : (N - 1);

    f32x2 mu2, mub2;
    mu2.x  = mu[i0];      mu2.y  = mu[i1];
    mub2.x = mu_bar[i0];  mub2.y = mu_bar[i1];
    const f32x2 rmu2  = rcp2(mu2 + splat2(EPS));
    const f32x2 rmub2 = rcp2(mub2 + splat2(EPS));
    const f32x2 nrmu2  = -rmu2;
    const f32x2 nrmub2 = -rmub2;

    f32x2 cons2[7];
    cons2[0].x = lw[i0];  cons2[0].y = lw[i1];
    cons2[1].x = h2o[i0]; cons2[1].y = h2o[i1];
    cons2[2].x = o3[i0];  cons2[2].y = o3[i1];
    cons2[3].x = co2[i0]; cons2[3].y = co2[i1];
    cons2[4].x = uu[i0];  cons2[4].y = uu[i1];
    cons2[5].x = n2o[i0]; cons2[5].y = n2o[i1];
    cons2[6].x = ch4[i0]; cons2[6].y = ch4[i1];

    f32x2 x2d[7], x2f[7];
#pragma unroll
    for (int f = 0; f < 7; ++f) { x2d[f] = cons2[f] * rmu2; x2f[f] = cons2[f] * rmub2; }

    int nsamp = N - base;
    if (nsamp > SPB) nsamp = SPB;
    float4* out4 = (float4*)out;

#pragma unroll
    for (int p = 0; p < 4; ++p) {
        const int cbase = p * 8;
        const int cend  = (p == 3) ? NCH : (cbase + 8);

        for (int c = cbase + wid; c < cend; c += 4) {
            f32x2 tau2;
            tau2.x = tau[(size_t)i0 * NCH + c];
            tau2.y = tau[(size_t)i1 * NCH + c];
            f32x2 td2 = expc2(tau2 * nrmu2);
            f32x2 tf2 = expc2(tau2 * nrmub2);

            f32x2 ed[3], ef[3];
            mlp7p(x2d, Wd0 + c * 35, bd0 + c * 5, Wd1 + c * 20, bd1 + c * 4,
                       Wd2 + c * 16, bd2 + c * 4, Wd3 + c * 12, bd3 + c * 3, ed);
            mlp7p(x2f, Wf0 + c * 35, bf0 + c * 5, Wf1 + c * 20, bf1 + c * 4,
                       Wf2 + c * 16, bf2 + c * 4, Wf3 + c * 12, bf3 + c * 3, ef);

            const int r = (c - cbase) * 2;
            obuf[lane * ROWF4 + r]            = make_float4(td2.x, tf2.x, ed[0].x, ed[1].x);
            obuf[lane * ROWF4 + r + 1]        = make_float4(ed[2].x, ef[0].x, ef[1].x, ef[2].x);
            obuf[(lane + 64) * ROWF4 + r]     = make_float4(td2.y, tf2.y, ed[0].y, ed[1].y);
            obuf[(lane + 64) * ROWF4 + r + 1] = make_float4(ed[2].y, ef[0].y, ef[1].y, ef[2].y);
        }
        __syncthreads();

        if (p < 3) {
            const int tot = nsamp * 16;
            for (int i = tid; i < tot; i += 256) {
                const int s = i >> 4, r = i & 15;
                out4[(size_t)(base + s) * 58 + p * 16 + r] = obuf[s * ROWF4 + r];
            }
        } else {
            const int tot = nsamp * 10;
            for (int i = tid; i < tot; i += 256) {
                const int s = i / 10, r = i - s * 10;
                out4[(size_t)(base + s) * 58 + 48 + r] = obuf[s * ROWF4 + r];
            }
        }
        __syncthreads();
    }
}

extern "C" void kernel_launch(void* const* d_in, const int* in_sizes, int n_in,
                              void* d_out, int out_size, void* d_ws, size_t ws_size,
                              hipStream_t stream) {
    const float* tau    = (const float*)d_in[0];
    const float* mu     = (const float*)d_in[1];
    const float* mu_bar = (const float*)d_in[2];
    const float* lw     = (const float*)d_in[3];
    const float* h2o    = (const float*)d_in[4];
    const float* o3     = (const float*)d_in[5];
    const float* co2    = (const float*)d_in[6];
    const float* uu     = (const float*)d_in[7];
    const float* n2o    = (const float*)d_in[8];
    const float* ch4    = (const float*)d_in[9];

    const float* Wd0 = (const float*)d_in[10];
    const float* bd0 = (const float*)d_in[11];
    const float* Wf0 = (const float*)d_in[12];
    const float* bf0 = (const float*)d_in[13];
    const float* Wd1 = (const float*)d_in[14];
    const float* bd1 = (const float*)d_in[15];
    const float* Wf1 = (const float*)d_in[16];
    const float* bf1 = (const float*)d_in[17];
    const float* Wd2 = (const float*)d_in[18];
    const float* bd2 = (const float*)d_in[19];
    const float* Wf2 = (const float*)d_in[20];
    const float* bf2 = (const float*)d_in[21];
    const float* Wd3 = (const float*)d_in[22];
    const float* bd3 = (const float*)d_in[23];
    const float* Wf3 = (const float*)d_in[24];
    const float* bf3 = (const float*)d_in[25];

    float* out = (float*)d_out;
    int N = in_sizes[1];  // mu has N elements

    int blocks = (N + SPB - 1) / SPB;
    lps_kernel<<<blocks, 256, 0, stream>>>(
        tau, mu, mu_bar, lw, h2o, o3, co2, uu, n2o, ch4,
        Wd0, bd0, Wf0, bf0, Wd1, bd1, Wf1, bf1,
        Wd2, bd2, Wf2, bf2, Wd3, bd3, Wf3, bf3,
        out, N);
}

// Round 4
// 83.541 us; speedup vs baseline: 2.7208x; 1.0044x over previous
//
#include <hip/hip_runtime.h>

#define EPS 1e-7f
#define NCH 29
#define SPB 128          // samples per block: 64 lanes x 2 packed (group0, group1)
#define ROWF4 59         // padded float4 stride per sample in obuf (58 + 1)

// MLP sizes: 7 -> 5 -> 4 -> 4 -> 3, per-channel weights.
// W0: [c][7][5]  b0: [c][5]
// W1: [c][5][4]  b1: [c][4]
// W2: [c][4][4]  b2: [c][4]
// W3: [c][4][3]  b3: [c][3]

typedef float f32x2 __attribute__((ext_vector_type(2)));

__device__ __forceinline__ f32x2 splat2(float v) { f32x2 r; r.x = v; r.y = v; return r; }
__device__ __forceinline__ f32x2 fma2(f32x2 a, f32x2 b, f32x2 c) {
    return __builtin_elementwise_fma(a, b, c);
}
__device__ __forceinline__ f32x2 max2(f32x2 a, f32x2 b) {
    return __builtin_elementwise_max(a, b);
}
__device__ __forceinline__ f32x2 expc2(f32x2 a) {
    f32x2 r; r.x = __expf(a.x); r.y = __expf(a.y); return r;
}
__device__ __forceinline__ f32x2 rcp2(f32x2 a) {
    f32x2 r; r.x = __builtin_amdgcn_rcpf(a.x); r.y = __builtin_amdgcn_rcpf(a.y); return r;
}

// Packed 2-sample MLP: weights are wave-uniform scalars (SGPR), data is f32x2
// (two samples per lane) -> v_pk_fma_f32.
__device__ __forceinline__ void mlp7p(const f32x2 x[7],
    const float* __restrict__ W0, const float* __restrict__ b0,
    const float* __restrict__ W1, const float* __restrict__ b1,
    const float* __restrict__ W2, const float* __restrict__ b2,
    const float* __restrict__ W3, const float* __restrict__ b3,
    f32x2 e[3])
{
    const f32x2 zero = splat2(0.0f);
    f32x2 h0[5];
#pragma unroll
    for (int h = 0; h < 5; ++h) {
        f32x2 a = splat2(b0[h]);
#pragma unroll
        for (int f = 0; f < 7; ++f) a = fma2(x[f], splat2(W0[f * 5 + h]), a);
        h0[h] = max2(a, zero);
    }
    f32x2 h1[4];
#pragma unroll
    for (int k = 0; k < 4; ++k) {
        f32x2 a = splat2(b1[k]);
#pragma unroll
        for (int h = 0; h < 5; ++h) a = fma2(h0[h], splat2(W1[h * 4 + k]), a);
        h1[k] = max2(a, zero);
    }
    f32x2 h2[4];
#pragma unroll
    for (int k = 0; k < 4; ++k) {
        f32x2 a = splat2(b2[k]);
#pragma unroll
        for (int h = 0; h < 4; ++h) a = fma2(h1[h], splat2(W2[h * 4 + k]), a);
        h2[k] = max2(a, zero);
    }
    f32x2 l[3];
#pragma unroll
    for (int k = 0; k < 3; ++k) {
        f32x2 a = splat2(b3[k]);
#pragma unroll
        for (int h = 0; h < 4; ++h) a = fma2(h2[h], splat2(W3[h * 3 + k]), a);
        l[k] = a;
    }
    f32x2 m = max2(l[0], max2(l[1], l[2]));
    f32x2 e0 = expc2(l[0] - m);
    f32x2 e1 = expc2(l[1] - m);
    f32x2 e2 = expc2(l[2] - m);
    f32x2 rs = rcp2(e0 + e1 + e2);
    e[0] = e0 * rs; e[1] = e1 * rs; e[2] = e2 * rs;
}

__global__ __launch_bounds__(512, 4) void lps_kernel(
    const float* __restrict__ tau, const float* __restrict__ mu, const float* __restrict__ mu_bar,
    const float* __restrict__ lw, const float* __restrict__ h2o, const float* __restrict__ o3,
    const float* __restrict__ co2, const float* __restrict__ uu, const float* __restrict__ n2o,
    const float* __restrict__ ch4,
    const float* __restrict__ Wd0, const float* __restrict__ bd0,
    const float* __restrict__ Wf0, const float* __restrict__ bf0,
    const float* __restrict__ Wd1, const float* __restrict__ bd1,
    const float* __restrict__ Wf1, const float* __restrict__ bf1,
    const float* __restrict__ Wd2, const float* __restrict__ bd2,
    const float* __restrict__ Wf2, const float* __restrict__ bf2,
    const float* __restrict__ Wd3, const float* __restrict__ bd3,
    const float* __restrict__ Wf3, const float* __restrict__ bf3,
    float* __restrict__ out, int N)
{
    __shared__ __align__(16) float4 obuf[64 * ROWF4];  // 60416 B

    const int tid  = threadIdx.x;
    const int lane = tid & 63;
    const int wid  = __builtin_amdgcn_readfirstlane(tid >> 6);

    const long long base = (long long)blockIdx.x * SPB;
    const int s0 = (int)base + lane;        // group-0 sample
    const int s1 = s0 + 64;                 // group-1 sample
    const int i0 = (s0 < N) ? s0 : (N - 1);
    const int i1 = (s1 < N) ? s1 : (N - 1);

    f32x2 mu2, mub2;
    mu2.x  = mu[i0];      mu2.y  = mu[i1];
    mub2.x = mu_bar[i0];  mub2.y = mu_bar[i1];
    const f32x2 rmu2   = rcp2(mu2 + splat2(EPS));
    const f32x2 rmub2  = rcp2(mub2 + splat2(EPS));
    const f32x2 nrmu2  = -rmu2;
    const f32x2 nrmub2 = -rmub2;

    f32x2 cons2[7];
    cons2[0].x = lw[i0];  cons2[0].y = lw[i1];
    cons2[1].x = h2o[i0]; cons2[1].y = h2o[i1];
    cons2[2].x = o3[i0];  cons2[2].y = o3[i1];
    cons2[3].x = co2[i0]; cons2[3].y = co2[i1];
    cons2[4].x = uu[i0];  cons2[4].y = uu[i1];
    cons2[5].x = n2o[i0]; cons2[5].y = n2o[i1];
    cons2[6].x = ch4[i0]; cons2[6].y = ch4[i1];

    f32x2 x2d[7], x2f[7];
#pragma unroll
    for (int f = 0; f < 7; ++f) { x2d[f] = cons2[f] * rmu2; x2f[f] = cons2[f] * rmub2; }

    // Group-1 (y-half) results held in registers, statically indexed.
    float ry[4][8];

#pragma unroll
    for (int it = 0; it < 4; ++it) {
        const int c = wid + it * 8;           // wave-uniform channel
        if (c < NCH) {
            f32x2 tau2;
            tau2.x = tau[(size_t)i0 * NCH + c];
            tau2.y = tau[(size_t)i1 * NCH + c];
            f32x2 td2 = expc2(tau2 * nrmu2);
            f32x2 tf2 = expc2(tau2 * nrmub2);

            f32x2 ed[3], ef[3];
            mlp7p(x2d, Wd0 + c * 35, bd0 + c * 5, Wd1 + c * 20, bd1 + c * 4,
                       Wd2 + c * 16, bd2 + c * 4, Wd3 + c * 12, bd3 + c * 3, ed);
            mlp7p(x2f, Wf0 + c * 35, bf0 + c * 5, Wf1 + c * 20, bf1 + c * 4,
                       Wf2 + c * 16, bf2 + c * 4, Wf3 + c * 12, bf3 + c * 3, ef);

            // x-half (group 0) -> LDS now
            obuf[lane * ROWF4 + c * 2]     = make_float4(td2.x, tf2.x, ed[0].x, ed[1].x);
            obuf[lane * ROWF4 + c * 2 + 1] = make_float4(ed[2].x, ef[0].x, ef[1].x, ef[2].x);
            // y-half (group 1) -> registers
            ry[it][0] = td2.y;   ry[it][1] = tf2.y;
            ry[it][2] = ed[0].y; ry[it][3] = ed[1].y;
            ry[it][4] = ed[2].y; ry[it][5] = ef[0].y;
            ry[it][6] = ef[1].y; ry[it][7] = ef[2].y;
        }
    }

    float4* out4 = (float4*)out;

    // ---- flush group 0 (contiguous 64*928B region, full lines) ----
    __syncthreads();
    {
        int n0 = N - (int)base; n0 = (n0 > 64) ? 64 : n0;
        if (n0 > 0) {
            const int tot = n0 * 58;
            const long long ob = base * 58;
            for (int i = tid; i < tot; i += 512) {
                const int s = i / 58, r = i - s * 58;
                out4[ob + i] = obuf[s * ROWF4 + r];
            }
        }
    }
    __syncthreads();

    // ---- group-1 results regs -> LDS ----
#pragma unroll
    for (int it = 0; it < 4; ++it) {
        const int c = wid + it * 8;
        if (c < NCH) {
            obuf[lane * ROWF4 + c * 2]     = make_float4(ry[it][0], ry[it][1], ry[it][2], ry[it][3]);
            obuf[lane * ROWF4 + c * 2 + 1] = make_float4(ry[it][4], ry[it][5], ry[it][6], ry[it][7]);
        }
    }
    __syncthreads();

    // ---- flush group 1 ----
    {
        int n1 = N - (int)base - 64; n1 = (n1 > 64) ? 64 : n1;
        if (n1 > 0) {
            const int tot = n1 * 58;
            const long long ob = (base + 64) * 58;
            for (int i = tid; i < tot; i += 512) {
                const int s = i / 58, r = i - s * 58;
                out4[ob + i] = obuf[s * ROWF4 + r];
            }
        }
    }
}

extern "C" void kernel_launch(void* const* d_in, const int* in_sizes, int n_in,
                              void* d_out, int out_size, void* d_ws, size_t ws_size,
                              hipStream_t stream) {
    const float* tau    = (const float*)d_in[0];
    const float* mu     = (const float*)d_in[1];
    const float* mu_bar = (const float*)d_in[2];
    const float* lw     = (const float*)d_in[3];
    const float* h2o    = (const float*)d_in[4];
    const float* o3     = (const float*)d_in[5];
    const float* co2    = (const float*)d_in[6];
    const float* uu     = (const float*)d_in[7];
    const float* n2o    = (const float*)d_in[8];
    const float* ch4    = (const float*)d_in[9];

    const float* Wd0 = (const float*)d_in[10];
    const float* bd0 = (const float*)d_in[11];
    const float* Wf0 = (const float*)d_in[12];
    const float* bf0 = (const float*)d_in[13];
    const float* Wd1 = (const float*)d_in[14];
    const float* bd1 = (const float*)d_in[15];
    const float* Wf1 = (const float*)d_in[16];
    const float* bf1 = (const float*)d_in[17];
    const float* Wd2 = (const float*)d_in[18];
    const float* bd2 = (const float*)d_in[19];
    const float* Wf2 = (const float*)d_in[20];
    const float* bf2 = (const float*)d_in[21];
    const float* Wd3 = (const float*)d_in[22];
    const float* bd3 = (const float*)d_in[23];
    const float* Wf3 = (const float*)d_in[24];
    const float* bf3 = (const float*)d_in[25];

    float* out = (float*)d_out;
    int N = in_sizes[1];  // mu has N elements

    int blocks = (N + SPB - 1) / SPB;
    lps_kernel<<<blocks, 512, 0, stream>>>(
        tau, mu, mu_bar, lw, h2o, o3, co2, uu, n2o, ch4,
        Wd0, bd0, Wf0, bf0, Wd1, bd1, Wf1, bf1,
        Wd2, bd2, Wf2, bf2, Wd3, bd3, Wf3, bf3,
        out, N);
}